// Round 13
// baseline (119956.494 us; speedup 1.0000x reference)
//
#include <hip/hip_runtime.h>
#include <math.h>

#define NB 32
#define TIN 512
#define TOUT 512
#define NENC 512
#define NATT 128
#define NU 1024
#define NG 4096
#define NPRE 256
#define NMEL 80

// ws offsets (floats)
#define WS_AH    0u
#define WS_AC    32768u
#define WS_DH    65536u
#define WS_DC    98304u
#define WS_ACTX  131072u
#define WS_AW    147456u
#define WS_AWCUM 163840u
#define WS_E     180224u
#define WS_PQ    196608u
#define WS_FLG   200704u                    // 16384 uints: 512 steps x 32
#define WS_ZD    217088u                    // 20*32*4096
#define WS_ZA    2838528u                   // 14*32*4096
#define WS_PM    4673536u                   // 32*512*128 [b][t][a]
#define WS_PRE   6770688u                   // 513*32*256 (row 512 = zeros)
#define WS_WBF   10973184u                  // bf16 weights (ushort)
#define WS_STATE_ZERO_BYTES (WS_ZD * 4u)
#define OUT_ALIGN ((size_t)NB * NMEL * TOUT + (size_t)NB * TOUT)

// bf16 weight sub-offsets (ushort elements)
#define BW_DIH 0u
#define BW_DHH 6291456u
#define BW_AIH 10485760u
#define BW_AHH 13631488u

__device__ __forceinline__ float fsigm(float x) { return 1.f / (1.f + __expf(-x)); }
__device__ __forceinline__ float ftanh(float x) { return 1.f - 2.f / (__expf(2.f * x) + 1.f); }
__device__ __forceinline__ float bf2f(unsigned short h) { return __uint_as_float((unsigned)h << 16); }

// write-through store to the coherence point (r7-proven)
__device__ __forceinline__ void st_wt(float* p, float v) {
    asm volatile("global_store_dword %0, %1, off sc0 sc1" :: "v"(p), "v"(v) : "memory");
}

// ---------------- weight pack: fp32 -> bf16 (RNE) ----------------
__global__ __launch_bounds__(256) void packbf_kernel(const float* __restrict__ src,
                                                     unsigned short* __restrict__ dst, int n) {
    for (int i = blockIdx.x * 256 + threadIdx.x; i < n; i += gridDim.x * 256) {
        unsigned u = __float_as_uint(src[i]);
        dst[i] = (unsigned short)((u + 0x7FFFu + ((u >> 16) & 1u)) >> 16);
    }
}

// ---------------- setup kernels (verified) ----------------
__global__ __launch_bounds__(256) void prenet1_kernel(const float* __restrict__ dec,
                                                      const float* __restrict__ w1,
                                                      float* __restrict__ pre) {
    int t = blockIdx.x;
    __shared__ float xl[NB][NMEL];
    for (int i = threadIdx.x; i < NB * NMEL; i += 256) {
        int b = i / NMEL, m = i % NMEL;
        xl[b][m] = (t == 0) ? 0.0f : dec[(b * NMEL + m) * TOUT + (t - 1)];
    }
    __syncthreads();
    int j = threadIdx.x;
    float acc[NB];
#pragma unroll
    for (int b = 0; b < NB; b++) acc[b] = 0.0f;
    for (int m = 0; m < NMEL; m++) {
        float w = w1[j * NMEL + m];
#pragma unroll
        for (int b = 0; b < NB; b++) acc[b] += xl[b][m] * w;
    }
    for (int b = 0; b < NB; b++) pre[((size_t)t * NB + b) * NPRE + j] = fmaxf(acc[b], 0.0f);
}

__global__ __launch_bounds__(256) void prenet2_kernel(const float* __restrict__ w2,
                                                      float* __restrict__ pre) {
    int t = blockIdx.x;
    __shared__ float hl[NB][NPRE];
    for (int i = threadIdx.x; i < NB * NPRE; i += 256)
        hl[i / NPRE][i % NPRE] = pre[(size_t)t * NB * NPRE + i];
    __syncthreads();
    int j = threadIdx.x;
    float acc[NB];
#pragma unroll
    for (int b = 0; b < NB; b++) acc[b] = 0.0f;
    for (int k = 0; k < NPRE; k++) {
        float w = w2[j * NPRE + k];
#pragma unroll
        for (int b = 0; b < NB; b++) acc[b] += hl[b][k] * w;
    }
    for (int b = 0; b < NB; b++) pre[((size_t)t * NB + b) * NPRE + j] = fmaxf(acc[b], 0.0f);
}

__global__ __launch_bounds__(128) void pm_kernel(const float* __restrict__ mem,
                                                 const float* __restrict__ mw,
                                                 float* __restrict__ pm) {
    int b = blockIdx.y, t0 = blockIdx.x * 4;
    __shared__ float ml[4][NENC];
    for (int i = threadIdx.x; i < 4 * NENC; i += 128)
        ml[i / NENC][i % NENC] = mem[((size_t)b * TIN + t0 + i / NENC) * NENC + (i % NENC)];
    __syncthreads();
    int a = threadIdx.x;
    float acc[4] = {0, 0, 0, 0};
    for (int e = 0; e < NENC; e++) {
        float w = mw[a * NENC + e];
#pragma unroll
        for (int tt = 0; tt < 4; tt++) acc[tt] += ml[tt][e] * w;
    }
    for (int tt = 0; tt < 4; tt++)
        pm[((size_t)b * TIN + t0 + tt) * NATT + a] = acc[tt];
}

// ---------------- z slice body (r12-verified, bf16 weights, wt option) ----------------
// slice s: 0-7 dwih@AH | 8-11 dwih@ACTX | 12-19 dwhh@DH |
//          20-21 awih@PRE(ts) | 22-25 awih@ACTX | 26-33 awhh@AH
__device__ __forceinline__ void z_slice_body(
        const unsigned short* __restrict__ wbf,
        const float* __restrict__ ws_base, const float* __restrict__ pre_t,
        float* __restrict__ zd, float* __restrict__ za, int s, int col, int wt) {
    const float* ah   = ws_base + WS_AH;
    const float* dh   = ws_base + WS_DH;
    const float* actx = ws_base + WS_ACTX;
    const unsigned short* W; const float* x; int xs;
    if (s < 8)       { W = wbf + BW_DIH + (size_t)col * 1536 + s * 128;              x = ah + s * 128;           xs = NU;   }
    else if (s < 12) { W = wbf + BW_DIH + (size_t)col * 1536 + 1024 + (s - 8) * 128; x = actx + (s - 8) * 128;   xs = NENC; }
    else if (s < 20) { W = wbf + BW_DHH + (size_t)col * 1024 + (s - 12) * 128;       x = dh + (s - 12) * 128;    xs = NU;   }
    else if (s < 22) { W = wbf + BW_AIH + (size_t)col * 768 + (s - 20) * 128;        x = pre_t + (s - 20) * 128; xs = NPRE; }
    else if (s < 26) { W = wbf + BW_AIH + (size_t)col * 768 + 256 + (s - 22) * 128;  x = actx + (s - 22) * 128;  xs = NENC; }
    else             { W = wbf + BW_AHH + (size_t)col * 1024 + (s - 26) * 128;       x = ah + (s - 26) * 128;    xs = NU;   }

    float acc[NB];
#pragma unroll
    for (int b = 0; b < NB; b++) acc[b] = 0.0f;
    for (int k4 = 0; k4 < 32; k4++) {
        ushort4 h4 = *(const ushort4*)(W + k4 * 4);
        float w0 = bf2f(h4.x), w1 = bf2f(h4.y), w2 = bf2f(h4.z), w3 = bf2f(h4.w);
#pragma unroll
        for (int b = 0; b < NB; b++) {
            float4 x4 = *(const float4*)(x + (size_t)b * xs + k4 * 4);  // wave-uniform -> scalar
            acc[b] = fmaf(w0, x4.x, acc[b]);
            acc[b] = fmaf(w1, x4.y, acc[b]);
            acc[b] = fmaf(w2, x4.z, acc[b]);
            acc[b] = fmaf(w3, x4.w, acc[b]);
        }
    }
    float* zp = ((s < 20) ? (zd + (size_t)s * NB * NG) : (za + (size_t)(s - 20) * NB * NG)) + col;
    if (wt) {
#pragma unroll
        for (int b = 0; b < NB; b++) st_wt(&zp[(size_t)b * NG], acc[b]);
    } else {
#pragma unroll
        for (int b = 0; b < NB; b++) zp[(size_t)b * NG] = acc[b];
    }
}

// ---------------- LA: z-main (832 blocks) || energies (512 blocks), 128 thr ----------------
__global__ __launch_bounds__(128) void la_kernel(
        const unsigned short* __restrict__ wbf, const float* __restrict__ pre_t1,
        const float* __restrict__ wc, const float* __restrict__ ldw,
        const float* __restrict__ vw, const int* __restrict__ mlen,
        float* __restrict__ ws) {
    __shared__ float sm[2336];
    int tid = threadIdx.x, bid = blockIdx.x;
    if (bid < 832) {
        int sidx = bid >> 5;
        int s = sidx < 8 ? sidx : (sidx < 18 ? sidx + 4 : sidx + 8);
        z_slice_body(wbf, ws, pre_t1, ws + WS_ZD, ws + WS_ZA, s, (bid & 31) * 128 + tid, 0);
        return;
    }
    // energies (r9-verified body)
    int eb = bid - 832;
    int b = eb >> 4, tc = eb & 15;
    int tt = tid & 31, sub = tid >> 5;
    int t = tc * 32 + tt;
    float* awl  = sm;          // 512
    float* cuml = sm + 512;    // 512
    float* locl = sm + 1024;   // 32*33
    float* pql  = sm + 2080;   // 128
    float* ep   = sm + 2208;   // 128
    for (int i = tid; i < TIN; i += 128) {
        awl[i]  = ws[WS_AW + b * TIN + i];
        cuml[i] = ws[WS_AWCUM + b * TIN + i];
    }
    for (int i = tid; i < NATT; i += 128) pql[i] = ws[WS_PQ + b * NATT + i];
    __syncthreads();
    for (int f = sub * 8; f < sub * 8 + 8; f++) {
        float s_ = 0.0f;
        const float* wA = wc + f * 62;
        const float* wB = wA + 31;
        for (int d = 0; d < 31; d++) {
            int tp = t + d - 15;
            if (tp >= 0 && tp < TIN) s_ += awl[tp] * wA[d] + cuml[tp] * wB[d];
        }
        locl[tt * 33 + f] = s_;
    }
    __syncthreads();
    float acc = 0.0f;
    const float* pmb = ws + WS_PM + ((size_t)b * TIN + t) * NATT;
    for (int a = sub * 32; a < sub * 32 + 32; a++) {
        float s_ = pql[a] + pmb[a];
        const float* lw = ldw + a * 32;
#pragma unroll
        for (int f = 0; f < 32; f++) s_ += locl[tt * 33 + f] * lw[f];
        acc += tanhf(s_) * vw[a];
    }
    ep[tt * 4 + sub] = acc;
    __syncthreads();
    if (sub == 0) {
        float ev = ep[tt * 4] + ep[tt * 4 + 1] + ep[tt * 4 + 2] + ep[tt * 4 + 3];
        if (t >= mlen[b]) ev = -3.0e38f;
        ws[WS_E + b * TIN + t] = ev;
    }
}

// ---------------- gates body (r9 arithmetic, re-phased main -> poll -> actx) ----------------
__device__ void gates_body(const float* __restrict__ abih, const float* __restrict__ abhh,
                           const float* __restrict__ qw,
                           const float* __restrict__ dbih, const float* __restrict__ dbhh,
                           const float* __restrict__ pjw, const float* __restrict__ pjb,
                           const float* __restrict__ gtw, const float* __restrict__ gtb,
                           float* __restrict__ ws, float* __restrict__ out, int t,
                           int poll, unsigned* zxf, int gid, int tid, float* sm) {
    if (gid < 32) {
        if (t < 0) return;
        int b = gid;
        float* DH = ws + WS_DH + (size_t)b * NU;
        float* DC = ws + WS_DC + (size_t)b * NU;
        float zi[2], zf[2], zg[2], zo[2];
#pragma unroll
        for (int j = 0; j < 2; ++j) {
            int u = tid + j * 512;
            zi[j] = dbih[u]          + dbhh[u];
            zf[j] = dbih[NU + u]     + dbhh[NU + u];
            zg[j] = dbih[2 * NU + u] + dbhh[2 * NU + u];
            zo[j] = dbih[3 * NU + u] + dbhh[3 * NU + u];
            for (int s = 0; s < 20; ++s) {
                if (s >= 8 && s < 12) continue;   // actx slices after poll
                const float* z = ws + WS_ZD + ((size_t)s * NB + b) * NG;
                zi[j] += z[u]; zf[j] += z[NU + u]; zg[j] += z[2 * NU + u]; zo[j] += z[3 * NU + u];
            }
        }
        if (poll && tid == 0) {
            while (__hip_atomic_fetch_add(zxf, 0u, __ATOMIC_RELAXED, __HIP_MEMORY_SCOPE_AGENT) < 64u)
                __builtin_amdgcn_s_sleep(8);
        }
        __syncthreads();
#pragma unroll
        for (int j = 0; j < 2; ++j) {
            int u = tid + j * 512;
            for (int s = 8; s < 12; ++s) {
                const float* z = ws + WS_ZD + ((size_t)s * NB + b) * NG;
                zi[j] += z[u]; zf[j] += z[NU + u]; zg[j] += z[2 * NU + u]; zo[j] += z[3 * NU + u];
            }
            float c = fsigm(zf[j]) * DC[u] + fsigm(zi[j]) * ftanh(zg[j]);
            float h = fsigm(zo[j]) * ftanh(c);
            DC[u] = c; DH[u] = h; sm[u] = h;
        }
        sm[NU + tid] = ws[WS_ACTX + b * NENC + tid];
        __syncthreads();
        int col = tid >> 2, q = tid & 3;
        if (col < 81) {
            const float* wr = (col < 80) ? (pjw + (size_t)col * 1536) : gtw;
            const float* d4 = sm + q * 384;
            const float* w4 = wr + q * 384;
            float s_ = 0.f;
#pragma unroll
            for (int k4 = 0; k4 < 96; k4++) {
                float4 hv = *(const float4*)(d4 + k4 * 4);
                float4 wv = *(const float4*)(w4 + k4 * 4);
                s_ = fmaf(hv.x, wv.x, s_); s_ = fmaf(hv.y, wv.y, s_);
                s_ = fmaf(hv.z, wv.z, s_); s_ = fmaf(hv.w, wv.w, s_);
            }
            s_ += __shfl_xor(s_, 1); s_ += __shfl_xor(s_, 2);
            if (q == 0) {
                s_ += (col < 80) ? pjb[col] : gtb[0];
                if (col < 80) out[((size_t)b * NMEL + col) * TOUT + t] = s_;
                else          out[(size_t)NB * NMEL * TOUT + (size_t)b * TOUT + t] = s_;
            }
        }
    } else {
        int b = gid - 32;
        float* AH = ws + WS_AH + (size_t)b * NU;
        float* AC = ws + WS_AC + (size_t)b * NU;
        float zi[2], zf[2], zg[2], zo[2];
#pragma unroll
        for (int j = 0; j < 2; ++j) {
            int u = tid + j * 512;
            zi[j] = abih[u]          + abhh[u];
            zf[j] = abih[NU + u]     + abhh[NU + u];
            zg[j] = abih[2 * NU + u] + abhh[2 * NU + u];
            zo[j] = abih[3 * NU + u] + abhh[3 * NU + u];
            for (int sA = 0; sA < 14; ++sA) {
                if (sA >= 2 && sA < 6) continue;  // actx slices after poll
                const float* z = ws + WS_ZA + ((size_t)sA * NB + b) * NG;
                zi[j] += z[u]; zf[j] += z[NU + u]; zg[j] += z[2 * NU + u]; zo[j] += z[3 * NU + u];
            }
        }
        if (poll && tid == 0) {
            while (__hip_atomic_fetch_add(zxf, 0u, __ATOMIC_RELAXED, __HIP_MEMORY_SCOPE_AGENT) < 64u)
                __builtin_amdgcn_s_sleep(8);
        }
        __syncthreads();
#pragma unroll
        for (int j = 0; j < 2; ++j) {
            int u = tid + j * 512;
            for (int sA = 2; sA < 6; ++sA) {
                const float* z = ws + WS_ZA + ((size_t)sA * NB + b) * NG;
                zi[j] += z[u]; zf[j] += z[NU + u]; zg[j] += z[2 * NU + u]; zo[j] += z[3 * NU + u];
            }
            float c = fsigm(zf[j]) * AC[u] + fsigm(zi[j]) * ftanh(zg[j]);
            float h = fsigm(zo[j]) * ftanh(c);
            AC[u] = c; AH[u] = h; sm[u] = h;
        }
        __syncthreads();
        int a = tid >> 2, q = tid & 3;
        if (a < NATT) {
            const float* qr = qw + (size_t)a * NU + q * 256;
            const float* h4 = sm + q * 256;
            float s_ = 0.f;
#pragma unroll
            for (int k4 = 0; k4 < 64; k4++) {
                float4 hv = *(const float4*)(h4 + k4 * 4);
                float4 wv = *(const float4*)(qr + k4 * 4);
                s_ = fmaf(hv.x, wv.x, s_); s_ = fmaf(hv.y, wv.y, s_);
                s_ = fmaf(hv.z, wv.z, s_); s_ = fmaf(hv.w, wv.w, s_);
            }
            s_ += __shfl_xor(s_, 1); s_ += __shfl_xor(s_, 2);
            if (q == 0) ws[WS_PQ + b * NATT + a] = s_;
        }
    }
}

// ---------------- LB: softmax+ctx (128) -> flag -> z-actx (64) -> flag -> gates (64) ----------------
__global__ __launch_bounds__(512) void lb_kernel(
        const unsigned short* __restrict__ wbf, const float* __restrict__ memory,
        const float* __restrict__ abih, const float* __restrict__ abhh,
        const float* __restrict__ qw,
        const float* __restrict__ dbih, const float* __restrict__ dbhh,
        const float* __restrict__ pjw, const float* __restrict__ pjb,
        const float* __restrict__ gtw, const float* __restrict__ gtb,
        float* __restrict__ ws, float* __restrict__ out, int t) {
    __shared__ float sm[1552];
    int tid = threadIdx.x, bid = blockIdx.x;
    unsigned* smf = (unsigned*)(ws + WS_FLG) + t * 32;
    unsigned* zxf = smf + 16;
    if (bid < 128) {
        int b = bid >> 2, ec = bid & 3;
        float* el = sm; float* red = sm + 512; float* part = sm + 528;
        float e0 = ws[WS_E + b * 512 + tid];
        float m = e0;
#pragma unroll
        for (int sh = 1; sh <= 32; sh <<= 1) m = fmaxf(m, __shfl_xor(m, sh));
        if ((tid & 63) == 0) red[tid >> 6] = m;
        __syncthreads();
        m = fmaxf(fmaxf(fmaxf(red[0], red[1]), fmaxf(red[2], red[3])),
                  fmaxf(fmaxf(red[4], red[5]), fmaxf(red[6], red[7])));
        float pv = __expf(e0 - m);
        float ss = pv;
#pragma unroll
        for (int sh = 1; sh <= 32; sh <<= 1) ss += __shfl_xor(ss, sh);
        if ((tid & 63) == 0) red[8 + (tid >> 6)] = ss;
        __syncthreads();
        float tot = red[8] + red[9] + red[10] + red[11] + red[12] + red[13] + red[14] + red[15];
        float aw = pv / tot;
        el[tid] = aw;
        if (ec == 0) {
            ws[WS_AW + b * 512 + tid] = aw;
            ws[WS_AWCUM + b * 512 + tid] += aw;
            (out + OUT_ALIGN)[((size_t)b * TOUT + t) * TIN + tid] = aw;
        }
        __syncthreads();
        int e = tid & 127, tq = tid >> 7;
        const float* mb = memory + (size_t)b * TIN * NENC + ec * 128 + e;
        float acc = 0.f;
        for (int u = tq * 128; u < tq * 128 + 128; ++u)
            acc = fmaf(el[u], mb[(size_t)u * NENC], acc);
        part[tq * 128 + e] = acc;
        __syncthreads();
        if (tid < 128)
            st_wt(&ws[WS_ACTX + b * NENC + ec * 128 + tid],
                  part[tid] + part[128 + tid] + part[256 + tid] + part[384 + tid]);
        __syncthreads();  // drains vmcnt(0) -> wt stores visible
        if (tid == 0)
            __hip_atomic_fetch_add(smf, 1u, __ATOMIC_RELAXED, __HIP_MEMORY_SCOPE_AGENT);
    } else if (bid < 192) {
        int zi = bid - 128;
        int sidx = zi >> 3;
        int s = (sidx < 4) ? 8 + sidx : 18 + sidx;    // 8-11, 22-25
        if (tid == 0) {
            while (__hip_atomic_fetch_add(smf, 0u, __ATOMIC_RELAXED, __HIP_MEMORY_SCOPE_AGENT) < 128u)
                __builtin_amdgcn_s_sleep(8);
        }
        __syncthreads();
        z_slice_body(wbf, ws, ws + WS_PRE, ws + WS_ZD, ws + WS_ZA, s, (zi & 7) * 512 + tid, 1);
        __syncthreads();  // drains vmcnt(0)
        if (tid == 0)
            __hip_atomic_fetch_add(zxf, 1u, __ATOMIC_RELAXED, __HIP_MEMORY_SCOPE_AGENT);
    } else {
        gates_body(abih, abhh, qw, dbih, dbhh, pjw, pjb, gtw, gtb,
                   ws, out, t, 1, zxf, bid - 192, tid, sm);
    }
}

// ---------------- prologue kernels ----------------
__global__ __launch_bounds__(128) void proz_kernel(const unsigned short* __restrict__ wbf,
                                                   float* __restrict__ ws) {
    z_slice_body(wbf, ws, ws + WS_PRE, ws + WS_ZD, ws + WS_ZA,
                 20 + (int)blockIdx.y, (int)blockIdx.x * 128 + (int)threadIdx.x, 0);
}

__global__ __launch_bounds__(512) void gates_kernel(
        const float* __restrict__ abih, const float* __restrict__ abhh,
        const float* __restrict__ qw,
        const float* __restrict__ dbih, const float* __restrict__ dbhh,
        const float* __restrict__ pjw, const float* __restrict__ pjb,
        const float* __restrict__ gtw, const float* __restrict__ gtb,
        float* __restrict__ ws, float* __restrict__ out, int t) {
    __shared__ float sm[1552];
    gates_body(abih, abhh, qw, dbih, dbhh, pjw, pjb, gtw, gtb,
               ws, out, t, 0, nullptr, (int)blockIdx.x, (int)threadIdx.x, sm);
}

extern "C" void kernel_launch(void* const* d_in, const int* in_sizes, int n_in,
                              void* d_out, int out_size, void* d_ws, size_t ws_size,
                              hipStream_t stream) {
    const float* memory = (const float*)d_in[0];
    const float* dec    = (const float*)d_in[1];
    const int*   mlen   = (const int*)d_in[2];
    const float* pw1    = (const float*)d_in[3];
    const float* pw2    = (const float*)d_in[4];
    const float* awih   = (const float*)d_in[5];
    const float* awhh   = (const float*)d_in[6];
    const float* abih   = (const float*)d_in[7];
    const float* abhh   = (const float*)d_in[8];
    const float* qw     = (const float*)d_in[9];
    const float* mw     = (const float*)d_in[10];
    const float* vw     = (const float*)d_in[11];
    const float* wc     = (const float*)d_in[12];
    const float* ldw    = (const float*)d_in[13];
    const float* dwih   = (const float*)d_in[14];
    const float* dwhh   = (const float*)d_in[15];
    const float* dbih   = (const float*)d_in[16];
    const float* dbhh   = (const float*)d_in[17];
    const float* pjw    = (const float*)d_in[18];
    const float* pjb    = (const float*)d_in[19];
    const float* gtw    = (const float*)d_in[20];
    const float* gtb    = (const float*)d_in[21];
    float* ws  = (float*)d_ws;
    float* out = (float*)d_out;
    unsigned short* wbf = (unsigned short*)(ws + WS_WBF);

    // zero state + flags (+ pre tail row)
    hipMemsetAsync(ws, 0, WS_STATE_ZERO_BYTES, stream);
    hipMemsetAsync(ws + WS_PRE + (size_t)512 * NB * NPRE, 0, (size_t)NB * NPRE * 4, stream);

    packbf_kernel<<<1024, 256, 0, stream>>>(dwih, wbf + BW_DIH, 4096 * 1536);
    packbf_kernel<<<1024, 256, 0, stream>>>(dwhh, wbf + BW_DHH, 4096 * 1024);
    packbf_kernel<<<1024, 256, 0, stream>>>(awih, wbf + BW_AIH, 4096 * 768);
    packbf_kernel<<<1024, 256, 0, stream>>>(awhh, wbf + BW_AHH, 4096 * 1024);

    prenet1_kernel<<<TOUT, 256, 0, stream>>>(dec, pw1, ws + WS_PRE);
    prenet2_kernel<<<TOUT, 256, 0, stream>>>(pw2, ws + WS_PRE);
    pm_kernel<<<dim3(TIN / 4, NB), 128, 0, stream>>>(memory, mw, ws + WS_PM);

    // prologue: za(0) all 14 slices (AH/ACTX zeroed), then agates+pq(0)
    proz_kernel<<<dim3(32, 14), 128, 0, stream>>>(wbf, ws);
    gates_kernel<<<64, 512, 0, stream>>>(abih, abhh, qw, dbih, dbhh, pjw, pjb,
                                         gtw, gtb, ws, out, -1);

    for (int t = 0; t < TOUT; ++t) {
        la_kernel<<<1344, 128, 0, stream>>>(
            wbf, ws + WS_PRE + (size_t)(t + 1) * NB * NPRE, wc, ldw, vw, mlen, ws);
        lb_kernel<<<256, 512, 0, stream>>>(
            wbf, memory, abih, abhh, qw, dbih, dbhh, pjw, pjb, gtw, gtb, ws, out, t);
    }
}

// Round 14
// 104798.450 us; speedup vs baseline: 1.1446x; 1.1446x over previous
//
#include <hip/hip_runtime.h>
#include <math.h>

#define NB 32
#define TIN 512
#define TOUT 512
#define NENC 512
#define NATT 128
#define NU 1024
#define NG 4096
#define NPRE 256
#define NMEL 80

// ws offsets (floats)
#define WS_AH    0u
#define WS_AC    32768u
#define WS_DH    65536u
#define WS_DC    98304u
#define WS_ACTX0 131072u                    // 2 x 16384 ping-pong
#define WS_AW    163840u
#define WS_AWCUM 180224u
#define WS_ZD    196608u                    // 20*32*4096
#define WS_ZA    2818048u                   // 14*32*4096
#define WS_PM    4653056u                   // 32*128*512 TRANSPOSED [b][a][t]
#define WS_PRE   6750208u                   // 513*32*256 (row 512 = zeros)
#define WS_WBF   10952704u                  // bf16 weights (ushort)
#define WS_STATE_ZERO_BYTES (WS_ZD * 4u)
#define OUT_ALIGN ((size_t)NB * NMEL * TOUT + (size_t)NB * TOUT)

// bf16 weight sub-offsets (ushort elements)
#define BW_DIH 0u
#define BW_DHH 6291456u
#define BW_AIH 10485760u
#define BW_AHH 13631488u

__device__ __forceinline__ float fsigm(float x) { return 1.f / (1.f + __expf(-x)); }
__device__ __forceinline__ float ftanh(float x) { return 1.f - 2.f / (__expf(2.f * x) + 1.f); }
__device__ __forceinline__ float bf2f(unsigned short h) { return __uint_as_float((unsigned)h << 16); }

// ---------------- weight pack: fp32 -> bf16 (RNE) ----------------
__global__ __launch_bounds__(256) void packbf_kernel(const float* __restrict__ src,
                                                     unsigned short* __restrict__ dst, int n) {
    for (int i = blockIdx.x * 256 + threadIdx.x; i < n; i += gridDim.x * 256) {
        unsigned u = __float_as_uint(src[i]);
        dst[i] = (unsigned short)((u + 0x7FFFu + ((u >> 16) & 1u)) >> 16);
    }
}

// ---------------- setup kernels (verified) ----------------
__global__ __launch_bounds__(256) void prenet1_kernel(const float* __restrict__ dec,
                                                      const float* __restrict__ w1,
                                                      float* __restrict__ pre) {
    int t = blockIdx.x;
    __shared__ float xl[NB][NMEL];
    for (int i = threadIdx.x; i < NB * NMEL; i += 256) {
        int b = i / NMEL, m = i % NMEL;
        xl[b][m] = (t == 0) ? 0.0f : dec[(b * NMEL + m) * TOUT + (t - 1)];
    }
    __syncthreads();
    int j = threadIdx.x;
    float acc[NB];
#pragma unroll
    for (int b = 0; b < NB; b++) acc[b] = 0.0f;
    for (int m = 0; m < NMEL; m++) {
        float w = w1[j * NMEL + m];
#pragma unroll
        for (int b = 0; b < NB; b++) acc[b] += xl[b][m] * w;
    }
    for (int b = 0; b < NB; b++) pre[((size_t)t * NB + b) * NPRE + j] = fmaxf(acc[b], 0.0f);
}

__global__ __launch_bounds__(256) void prenet2_kernel(const float* __restrict__ w2,
                                                      float* __restrict__ pre) {
    int t = blockIdx.x;
    __shared__ float hl[NB][NPRE];
    for (int i = threadIdx.x; i < NB * NPRE; i += 256)
        hl[i / NPRE][i % NPRE] = pre[(size_t)t * NB * NPRE + i];
    __syncthreads();
    int j = threadIdx.x;
    float acc[NB];
#pragma unroll
    for (int b = 0; b < NB; b++) acc[b] = 0.0f;
    for (int k = 0; k < NPRE; k++) {
        float w = w2[j * NPRE + k];
#pragma unroll
        for (int b = 0; b < NB; b++) acc[b] += hl[b][k] * w;
    }
    for (int b = 0; b < NB; b++) pre[((size_t)t * NB + b) * NPRE + j] = fmaxf(acc[b], 0.0f);
}

// processed_memory TRANSPOSED: pmt[b][a][t]  (r5-r8 verified)
__global__ __launch_bounds__(128) void pmt_kernel(const float* __restrict__ mem,
                                                  const float* __restrict__ mw,
                                                  float* __restrict__ pmt) {
    int b = blockIdx.y, t0 = blockIdx.x * 4;
    __shared__ float ml[4][NENC];
    for (int i = threadIdx.x; i < 4 * NENC; i += 128)
        ml[i / NENC][i % NENC] = mem[((size_t)b * TIN + t0 + i / NENC) * NENC + (i % NENC)];
    __syncthreads();
    int a = threadIdx.x;
    float acc[4] = {0, 0, 0, 0};
    for (int e = 0; e < NENC; e++) {
        float w = mw[a * NENC + e];
#pragma unroll
        for (int tt = 0; tt < 4; tt++) acc[tt] += ml[tt][e] * w;
    }
    *(float4*)&pmt[((size_t)b * NATT + a) * TIN + t0] = make_float4(acc[0], acc[1], acc[2], acc[3]);
}

// ---------------- Z: all 34 z slices (r12-verified body, explicit actx ptr) ----------------
// slice s: 0-7 dwih@AH | 8-11 dwih@ACTX | 12-19 dwhh@DH |
//          20-21 awih@PRE(ts) | 22-25 awih@ACTX | 26-33 awhh@AH
__global__ __launch_bounds__(256) void z_all_kernel(
        const unsigned short* __restrict__ wbf,
        const float* __restrict__ ws_base, const float* __restrict__ actx,
        const float* __restrict__ pre_t,
        float* __restrict__ zd, float* __restrict__ za) {
    int col = blockIdx.x * 256 + threadIdx.x;
    int s = blockIdx.y;
    const float* ah = ws_base + WS_AH;
    const float* dh = ws_base + WS_DH;
    const unsigned short* W; const float* x; int xs;
    if (s < 8)       { W = wbf + BW_DIH + (size_t)col * 1536 + s * 128;              x = ah + s * 128;           xs = NU;   }
    else if (s < 12) { W = wbf + BW_DIH + (size_t)col * 1536 + 1024 + (s - 8) * 128; x = actx + (s - 8) * 128;   xs = NENC; }
    else if (s < 20) { W = wbf + BW_DHH + (size_t)col * 1024 + (s - 12) * 128;       x = dh + (s - 12) * 128;    xs = NU;   }
    else if (s < 22) { W = wbf + BW_AIH + (size_t)col * 768 + (s - 20) * 128;        x = pre_t + (s - 20) * 128; xs = NPRE; }
    else if (s < 26) { W = wbf + BW_AIH + (size_t)col * 768 + 256 + (s - 22) * 128;  x = actx + (s - 22) * 128;  xs = NENC; }
    else             { W = wbf + BW_AHH + (size_t)col * 1024 + (s - 26) * 128;       x = ah + (s - 26) * 128;    xs = NU;   }

    float acc[NB];
#pragma unroll
    for (int b = 0; b < NB; b++) acc[b] = 0.0f;
    for (int k4 = 0; k4 < 32; k4++) {
        ushort4 h4 = *(const ushort4*)(W + k4 * 4);
        float w0 = bf2f(h4.x), w1 = bf2f(h4.y), w2 = bf2f(h4.z), w3 = bf2f(h4.w);
#pragma unroll
        for (int b = 0; b < NB; b++) {
            float4 x4 = *(const float4*)(x + (size_t)b * xs + k4 * 4);  // wave-uniform -> scalar
            acc[b] = fmaf(w0, x4.x, acc[b]);
            acc[b] = fmaf(w1, x4.y, acc[b]);
            acc[b] = fmaf(w2, x4.z, acc[b]);
            acc[b] = fmaf(w3, x4.w, acc[b]);
        }
    }
    float* zp = ((s < 20) ? (zd + (size_t)s * NB * NG) : (za + (size_t)(s - 20) * NB * NG)) + col;
#pragma unroll
    for (int b = 0; b < NB; b++) zp[(size_t)b * NG] = acc[b];
}

// ---------------- G: dgates+proj(t) [0-31] || attn-mega(t+1) [32-63] ----------------
__global__ __launch_bounds__(512) void g_kernel(
        const float* __restrict__ abih, const float* __restrict__ abhh,
        const float* __restrict__ qw,
        const float* __restrict__ dbih, const float* __restrict__ dbhh,
        const float* __restrict__ pjw, const float* __restrict__ pjb,
        const float* __restrict__ gtw, const float* __restrict__ gtb,
        const float* __restrict__ memory, const int* __restrict__ mlen,
        const float* __restrict__ wc, const float* __restrict__ ldw,
        const float* __restrict__ vw,
        float* __restrict__ ws, float* __restrict__ out, int t) {
    __shared__ float sm[1552];
    int tid = threadIdx.x, bid = blockIdx.x;
    float* actx_cur = ws + WS_ACTX0 + (size_t)(t & 1) * 16384;
    float* actx_nxt = ws + WS_ACTX0 + (size_t)((t + 1) & 1) * 16384;

    if (bid < 32) {
        if (t < 0) return;
        int b = bid;
        float* DH = ws + WS_DH + (size_t)b * NU;
        float* DC = ws + WS_DC + (size_t)b * NU;
        for (int u = tid; u < NU; u += 512) {
            float zi = dbih[u]          + dbhh[u];
            float zf = dbih[NU + u]     + dbhh[NU + u];
            float zg = dbih[2 * NU + u] + dbhh[2 * NU + u];
            float zo = dbih[3 * NU + u] + dbhh[3 * NU + u];
            for (int s = 0; s < 20; s++) {
                const float* z = ws + WS_ZD + ((size_t)s * NB + b) * NG;
                zi += z[u]; zf += z[NU + u]; zg += z[2 * NU + u]; zo += z[3 * NU + u];
            }
            float c = fsigm(zf) * DC[u] + fsigm(zi) * ftanh(zg);
            float h = fsigm(zo) * ftanh(c);
            DC[u] = c; DH[u] = h; sm[u] = h;
        }
        for (int i = tid; i < NENC; i += 512) sm[NU + i] = actx_cur[b * NENC + i];
        __syncthreads();
        int col = tid >> 2, q = tid & 3;
        if (col < 81) {
            const float* wr = (col < 80) ? (pjw + (size_t)col * 1536) : gtw;
            const float* d4 = sm + q * 384;
            const float* w4 = wr + q * 384;
            float s = 0.f;
#pragma unroll
            for (int k4 = 0; k4 < 96; k4++) {
                float4 hv = *(const float4*)(d4 + k4 * 4);
                float4 wv = *(const float4*)(w4 + k4 * 4);
                s = fmaf(hv.x, wv.x, s); s = fmaf(hv.y, wv.y, s);
                s = fmaf(hv.z, wv.z, s); s = fmaf(hv.w, wv.w, s);
            }
            s += __shfl_xor(s, 1); s += __shfl_xor(s, 2);
            if (q == 0) {
                s += (col < 80) ? pjb[col] : gtb[0];
                if (col < 80) out[((size_t)b * NMEL + col) * TOUT + t] = s;
                else          out[(size_t)NB * NMEL * TOUT + (size_t)b * TOUT + t] = s;
            }
        }
        return;
    }

    // attn-mega for step t+1
    if (t + 1 >= TOUT) return;
    int b = bid - 32;
    // 1) agates (r12-verified arithmetic)
    {
        float* AH = ws + WS_AH + (size_t)b * NU;
        float* AC = ws + WS_AC + (size_t)b * NU;
        float* ahl = sm;
        for (int u = tid; u < NU; u += 512) {
            float zi = abih[u]          + abhh[u];
            float zf = abih[NU + u]     + abhh[NU + u];
            float zg = abih[2 * NU + u] + abhh[2 * NU + u];
            float zo = abih[3 * NU + u] + abhh[3 * NU + u];
            for (int s = 0; s < 14; s++) {
                const float* z = ws + WS_ZA + ((size_t)s * NB + b) * NG;
                zi += z[u]; zf += z[NU + u]; zg += z[2 * NU + u]; zo += z[3 * NU + u];
            }
            float c = fsigm(zf) * AC[u] + fsigm(zi) * ftanh(zg);
            float h = fsigm(zo) * ftanh(c);
            AC[u] = c; AH[u] = h; ahl[u] = h;
        }
        __syncthreads();
        // 2) pq -> LDS
        int a = tid >> 2, q = tid & 3;
        const float* qr = qw + (size_t)a * NU + q * 256;
        const float* h4 = ahl + q * 256;
        float s = 0.f;
#pragma unroll
        for (int k4 = 0; k4 < 64; k4++) {
            float4 hv = *(const float4*)(h4 + k4 * 4);
            float4 wv = *(const float4*)(qr + k4 * 4);
            s = fmaf(hv.x, wv.x, s); s = fmaf(hv.y, wv.y, s);
            s = fmaf(hv.z, wv.z, s); s = fmaf(hv.w, wv.w, s);
        }
        s += __shfl_xor(s, 1); s += __shfl_xor(s, 2);
        if (q == 0) sm[1024 + a] = s;     // pql
    }
    __syncthreads();
    // 3) energies + softmax + ctx (r5-r8 verified bodies)
    float* awl = sm, *cuml = sm + 512, *pql = sm + 1024, *red = sm + 1152;
    float cumv = ws[WS_AWCUM + b * 512 + tid];
    float awv  = ws[WS_AW + b * 512 + tid];
    awl[tid] = awv; cuml[tid] = cumv;     // overwrites ahl (done with it)
    __syncthreads();
    int tpos = tid;
    float loc[32];
#pragma unroll
    for (int f = 0; f < 32; ++f) loc[f] = 0.f;
    for (int d = 0; d < 31; ++d) {
        int tp = tpos + d - 15;
        int tc = min(max(tp, 0), 511);
        bool ok = (tp >= 0) && (tp < 512);
        float a_ = ok ? awl[tc] : 0.f;
        float c_ = ok ? cuml[tc] : 0.f;
#pragma unroll
        for (int f = 0; f < 32; ++f)
            loc[f] = fmaf(a_, wc[f * 62 + d], fmaf(c_, wc[f * 62 + 31 + d], loc[f]));
    }
    float e = 0.f;
    const float* pmt = ws + WS_PM + (size_t)b * NATT * TIN + tpos;
    for (int a = 0; a < NATT; ++a) {
        float s = pql[a] + pmt[(size_t)a * TIN];
#pragma unroll
        for (int f = 0; f < 32; ++f) s = fmaf(loc[f], ldw[a * 32 + f], s);
        e = fmaf(ftanh(s), vw[a], e);
    }
    if (tpos >= mlen[b]) e = -3.0e38f;
    float m = e;
#pragma unroll
    for (int sh = 1; sh <= 32; sh <<= 1) m = fmaxf(m, __shfl_xor(m, sh));
    if ((tid & 63) == 0) red[tid >> 6] = m;
    __syncthreads();
    m = fmaxf(fmaxf(fmaxf(red[0], red[1]), fmaxf(red[2], red[3])),
              fmaxf(fmaxf(red[4], red[5]), fmaxf(red[6], red[7])));
    float pv = __expf(e - m);
    float ss = pv;
#pragma unroll
    for (int sh = 1; sh <= 32; sh <<= 1) ss += __shfl_xor(ss, sh);
    if ((tid & 63) == 0) red[8 + (tid >> 6)] = ss;
    __syncthreads();
    float tot = red[8] + red[9] + red[10] + red[11] + red[12] + red[13] + red[14] + red[15];
    float aw = pv / tot;
    ws[WS_AW + b * 512 + tid] = aw;
    ws[WS_AWCUM + b * 512 + tid] = cumv + aw;
    (out + OUT_ALIGN)[((size_t)b * TOUT + (t + 1)) * TIN + tid] = aw;
    __syncthreads();
    awl[tid] = aw;
    __syncthreads();
    const float* mb = memory + (size_t)b * TIN * NENC + tid;
    float a0 = 0.f, a1 = 0.f, a2 = 0.f, a3 = 0.f;
    for (int tt = 0; tt < TIN; tt += 4) {
        a0 = fmaf(awl[tt],     mb[(size_t)tt * NENC], a0);
        a1 = fmaf(awl[tt + 1], mb[(size_t)(tt + 1) * NENC], a1);
        a2 = fmaf(awl[tt + 2], mb[(size_t)(tt + 2) * NENC], a2);
        a3 = fmaf(awl[tt + 3], mb[(size_t)(tt + 3) * NENC], a3);
    }
    actx_nxt[b * NENC + tid] = (a0 + a1) + (a2 + a3);
}

extern "C" void kernel_launch(void* const* d_in, const int* in_sizes, int n_in,
                              void* d_out, int out_size, void* d_ws, size_t ws_size,
                              hipStream_t stream) {
    const float* memory = (const float*)d_in[0];
    const float* dec    = (const float*)d_in[1];
    const int*   mlen   = (const int*)d_in[2];
    const float* pw1    = (const float*)d_in[3];
    const float* pw2    = (const float*)d_in[4];
    const float* awih   = (const float*)d_in[5];
    const float* awhh   = (const float*)d_in[6];
    const float* abih   = (const float*)d_in[7];
    const float* abhh   = (const float*)d_in[8];
    const float* qw     = (const float*)d_in[9];
    const float* mw     = (const float*)d_in[10];
    const float* vw     = (const float*)d_in[11];
    const float* wc     = (const float*)d_in[12];
    const float* ldw    = (const float*)d_in[13];
    const float* dwih   = (const float*)d_in[14];
    const float* dwhh   = (const float*)d_in[15];
    const float* dbih   = (const float*)d_in[16];
    const float* dbhh   = (const float*)d_in[17];
    const float* pjw    = (const float*)d_in[18];
    const float* pjb    = (const float*)d_in[19];
    const float* gtw    = (const float*)d_in[20];
    const float* gtb    = (const float*)d_in[21];
    float* ws  = (float*)d_ws;
    float* out = (float*)d_out;
    unsigned short* wbf = (unsigned short*)(ws + WS_WBF);

    hipMemsetAsync(ws, 0, WS_STATE_ZERO_BYTES, stream);
    hipMemsetAsync(ws + WS_PRE + (size_t)512 * NB * NPRE, 0, (size_t)NB * NPRE * 4, stream);

    packbf_kernel<<<1024, 256, 0, stream>>>(dwih, wbf + BW_DIH, 4096 * 1536);
    packbf_kernel<<<1024, 256, 0, stream>>>(dwhh, wbf + BW_DHH, 4096 * 1024);
    packbf_kernel<<<1024, 256, 0, stream>>>(awih, wbf + BW_AIH, 4096 * 768);
    packbf_kernel<<<1024, 256, 0, stream>>>(awhh, wbf + BW_AHH, 4096 * 1024);

    prenet1_kernel<<<TOUT, 256, 0, stream>>>(dec, pw1, ws + WS_PRE);
    prenet2_kernel<<<TOUT, 256, 0, stream>>>(pw2, ws + WS_PRE);
    pmt_kernel<<<dim3(TIN / 4, NB), 128, 0, stream>>>(memory, mw, ws + WS_PM);

    // prologue: za(0) via z_all on zeroed state (actx = buffer 1, zeros);
    // then G(-1): attn-mega only -> AH(0), aw(0), alignments row 0, ACTX(0) buf 0
    z_all_kernel<<<dim3(16, 34), 256, 0, stream>>>(
        wbf, ws, ws + WS_ACTX0 + 16384, ws + WS_PRE, ws + WS_ZD, ws + WS_ZA);
    g_kernel<<<64, 512, 0, stream>>>(abih, abhh, qw, dbih, dbhh, pjw, pjb, gtw, gtb,
                                     memory, mlen, wc, ldw, vw, ws, out, -1);

    for (int t = 0; t < TOUT; ++t) {
        z_all_kernel<<<dim3(16, 34), 256, 0, stream>>>(
            wbf, ws, ws + WS_ACTX0 + (size_t)(t & 1) * 16384,
            ws + WS_PRE + (size_t)(t + 1) * NB * NPRE, ws + WS_ZD, ws + WS_ZA);
        g_kernel<<<64, 512, 0, stream>>>(abih, abhh, qw, dbih, dbhh, pjw, pjb, gtw, gtb,
                                         memory, mlen, wc, ldw, vw, ws, out, t);
    }
}

// Round 15
// 85298.938 us; speedup vs baseline: 1.4063x; 1.2286x over previous
//
#include <hip/hip_runtime.h>
#include <math.h>

#define NB 32
#define TIN 512
#define TOUT 512
#define NENC 512
#define NATT 128
#define NU 1024
#define NG 4096
#define NPRE 256
#define NMEL 80

// ws offsets (floats)
#define WS_AH    0u
#define WS_AC    32768u
#define WS_DH    65536u
#define WS_DC    98304u
#define WS_ACTX  131072u
#define WS_AW    147456u
#define WS_AWCUM 163840u
#define WS_E     180224u
#define WS_PQ    196608u
#define WS_FLG   200704u                    // 1024 uints (per-step monotone counters)
#define WS_ZD    201728u                    // 20*32*4096
#define WS_ZA    2823168u                   // 14*32*4096
#define WS_PM    4658176u                   // 32*512*128 [b][t][a]
#define WS_PRE   6755328u                   // 513*32*256 (row 512 = zeros)
#define WS_WBF   10957824u                  // bf16 weights (ushort)
#define WS_STATE_ZERO_BYTES (WS_ZD * 4u)
#define OUT_ALIGN ((size_t)NB * NMEL * TOUT + (size_t)NB * TOUT)

// bf16 weight sub-offsets (ushort elements)
#define BW_DIH 0u
#define BW_DHH 6291456u
#define BW_AIH 10485760u
#define BW_AHH 13631488u

__device__ __forceinline__ float fsigm(float x) { return 1.f / (1.f + __expf(-x)); }
__device__ __forceinline__ float ftanh(float x) { return 1.f - 2.f / (__expf(2.f * x) + 1.f); }
__device__ __forceinline__ float bf2f(unsigned short h) { return __uint_as_float((unsigned)h << 16); }

// write-through store to the coherence point (r7-proven)
__device__ __forceinline__ void st_wt(float* p, float v) {
    asm volatile("global_store_dword %0, %1, off sc0 sc1" :: "v"(p), "v"(v) : "memory");
}

// ---------------- weight pack: fp32 -> bf16 (RNE) ----------------
__global__ __launch_bounds__(256) void packbf_kernel(const float* __restrict__ src,
                                                     unsigned short* __restrict__ dst, int n) {
    for (int i = blockIdx.x * 256 + threadIdx.x; i < n; i += gridDim.x * 256) {
        unsigned u = __float_as_uint(src[i]);
        dst[i] = (unsigned short)((u + 0x7FFFu + ((u >> 16) & 1u)) >> 16);
    }
}

// ---------------- setup kernels (verified) ----------------
__global__ __launch_bounds__(256) void prenet1_kernel(const float* __restrict__ dec,
                                                      const float* __restrict__ w1,
                                                      float* __restrict__ pre) {
    int t = blockIdx.x;
    __shared__ float xl[NB][NMEL];
    for (int i = threadIdx.x; i < NB * NMEL; i += 256) {
        int b = i / NMEL, m = i % NMEL;
        xl[b][m] = (t == 0) ? 0.0f : dec[(b * NMEL + m) * TOUT + (t - 1)];
    }
    __syncthreads();
    int j = threadIdx.x;
    float acc[NB];
#pragma unroll
    for (int b = 0; b < NB; b++) acc[b] = 0.0f;
    for (int m = 0; m < NMEL; m++) {
        float w = w1[j * NMEL + m];
#pragma unroll
        for (int b = 0; b < NB; b++) acc[b] += xl[b][m] * w;
    }
    for (int b = 0; b < NB; b++) pre[((size_t)t * NB + b) * NPRE + j] = fmaxf(acc[b], 0.0f);
}

__global__ __launch_bounds__(256) void prenet2_kernel(const float* __restrict__ w2,
                                                      float* __restrict__ pre) {
    int t = blockIdx.x;
    __shared__ float hl[NB][NPRE];
    for (int i = threadIdx.x; i < NB * NPRE; i += 256)
        hl[i / NPRE][i % NPRE] = pre[(size_t)t * NB * NPRE + i];
    __syncthreads();
    int j = threadIdx.x;
    float acc[NB];
#pragma unroll
    for (int b = 0; b < NB; b++) acc[b] = 0.0f;
    for (int k = 0; k < NPRE; k++) {
        float w = w2[j * NPRE + k];
#pragma unroll
        for (int b = 0; b < NB; b++) acc[b] += hl[b][k] * w;
    }
    for (int b = 0; b < NB; b++) pre[((size_t)t * NB + b) * NPRE + j] = fmaxf(acc[b], 0.0f);
}

__global__ __launch_bounds__(128) void pm_kernel(const float* __restrict__ mem,
                                                 const float* __restrict__ mw,
                                                 float* __restrict__ pm) {
    int b = blockIdx.y, t0 = blockIdx.x * 4;
    __shared__ float ml[4][NENC];
    for (int i = threadIdx.x; i < 4 * NENC; i += 128)
        ml[i / NENC][i % NENC] = mem[((size_t)b * TIN + t0 + i / NENC) * NENC + (i % NENC)];
    __syncthreads();
    int a = threadIdx.x;
    float acc[4] = {0, 0, 0, 0};
    for (int e = 0; e < NENC; e++) {
        float w = mw[a * NENC + e];
#pragma unroll
        for (int tt = 0; tt < 4; tt++) acc[tt] += ml[tt][e] * w;
    }
    for (int tt = 0; tt < 4; tt++)
        pm[((size_t)b * TIN + t0 + tt) * NATT + a] = acc[tt];
}

// ---------------- Z: all 34 z slices (r12-verified body) ----------------
// slice s: 0-7 dwih@AH | 8-11 dwih@ACTX | 12-19 dwhh@DH |
//          20-21 awih@PRE(ts) | 22-25 awih@ACTX | 26-33 awhh@AH
__global__ __launch_bounds__(256) void z_all_kernel(
        const unsigned short* __restrict__ wbf,
        const float* __restrict__ ws_base, const float* __restrict__ pre_t,
        float* __restrict__ zd, float* __restrict__ za) {
    int col = blockIdx.x * 256 + threadIdx.x;
    int s = blockIdx.y;
    const float* ah   = ws_base + WS_AH;
    const float* dh   = ws_base + WS_DH;
    const float* actx = ws_base + WS_ACTX;
    const unsigned short* W; const float* x; int xs;
    if (s < 8)       { W = wbf + BW_DIH + (size_t)col * 1536 + s * 128;              x = ah + s * 128;           xs = NU;   }
    else if (s < 12) { W = wbf + BW_DIH + (size_t)col * 1536 + 1024 + (s - 8) * 128; x = actx + (s - 8) * 128;   xs = NENC; }
    else if (s < 20) { W = wbf + BW_DHH + (size_t)col * 1024 + (s - 12) * 128;       x = dh + (s - 12) * 128;    xs = NU;   }
    else if (s < 22) { W = wbf + BW_AIH + (size_t)col * 768 + (s - 20) * 128;        x = pre_t + (s - 20) * 128; xs = NPRE; }
    else if (s < 26) { W = wbf + BW_AIH + (size_t)col * 768 + 256 + (s - 22) * 128;  x = actx + (s - 22) * 128;  xs = NENC; }
    else             { W = wbf + BW_AHH + (size_t)col * 1024 + (s - 26) * 128;       x = ah + (s - 26) * 128;    xs = NU;   }

    float acc[NB];
#pragma unroll
    for (int b = 0; b < NB; b++) acc[b] = 0.0f;
    for (int k4 = 0; k4 < 32; k4++) {
        ushort4 h4 = *(const ushort4*)(W + k4 * 4);
        float w0 = bf2f(h4.x), w1 = bf2f(h4.y), w2 = bf2f(h4.z), w3 = bf2f(h4.w);
#pragma unroll
        for (int b = 0; b < NB; b++) {
            float4 x4 = *(const float4*)(x + (size_t)b * xs + k4 * 4);  // wave-uniform -> scalar
            acc[b] = fmaf(w0, x4.x, acc[b]);
            acc[b] = fmaf(w1, x4.y, acc[b]);
            acc[b] = fmaf(w2, x4.z, acc[b]);
            acc[b] = fmaf(w3, x4.w, acc[b]);
        }
    }
    float* zp = ((s < 20) ? (zd + (size_t)s * NB * NG) : (za + (size_t)(s - 20) * NB * NG)) + col;
#pragma unroll
    for (int b = 0; b < NB; b++) zp[(size_t)b * NG] = acc[b];
}

// ---------------- SM: softmax + context (r12 verbatim) ----------------
__global__ __launch_bounds__(256) void softmax_ctx_kernel(const float* __restrict__ mem,
                                                          const float* __restrict__ E,
                                                          float* __restrict__ AW,
                                                          float* __restrict__ AWCUM,
                                                          float* __restrict__ ACTX,
                                                          float* __restrict__ out_align, int step) {
    int b = blockIdx.y, ec = blockIdx.x;
    __shared__ float el[TIN];
    __shared__ float red[256];
    __shared__ float part[4][64];
    const float* Eb = E + b * TIN;
    for (int i = threadIdx.x; i < TIN; i += 256) el[i] = Eb[i];
    __syncthreads();
    red[threadIdx.x] = fmaxf(el[threadIdx.x], el[threadIdx.x + 256]);
    __syncthreads();
    for (int s = 128; s > 0; s >>= 1) {
        if (threadIdx.x < s) red[threadIdx.x] = fmaxf(red[threadIdx.x], red[threadIdx.x + s]);
        __syncthreads();
    }
    float mx = red[0];
    __syncthreads();
    float p0 = __expf(el[threadIdx.x] - mx), p1 = __expf(el[threadIdx.x + 256] - mx);
    el[threadIdx.x] = p0; el[threadIdx.x + 256] = p1;
    red[threadIdx.x] = p0 + p1;
    __syncthreads();
    for (int s = 128; s > 0; s >>= 1) {
        if (threadIdx.x < s) red[threadIdx.x] += red[threadIdx.x + s];
        __syncthreads();
    }
    float inv = 1.0f / red[0];
    int ei = ec * 64 + (threadIdx.x & 63), tp4 = threadIdx.x >> 6;
    float acc = 0.0f;
    const float* mb = mem + (size_t)b * TIN * NENC + ei;
    for (int t = tp4 * 128; t < tp4 * 128 + 128; t++) acc += el[t] * mb[(size_t)t * NENC];
    part[tp4][threadIdx.x & 63] = acc;
    __syncthreads();
    if (threadIdx.x < 64) {
        float ctx = (part[0][threadIdx.x] + part[1][threadIdx.x] +
                     part[2][threadIdx.x] + part[3][threadIdx.x]) * inv;
        ACTX[b * NENC + ec * 64 + threadIdx.x] = ctx;
    }
    if (ec == 0) {
        for (int i = threadIdx.x; i < TIN; i += 256) {
            float a_ = el[i] * inv;
            AW[b * TIN + i] = a_;
            AWCUM[b * TIN + i] += a_;
            out_align[((size_t)b * TOUT + step) * TIN + i] = a_;
        }
    }
}

// ---------------- GE: dgates+proj(t) [0-31] || agates+pq(t+1)+flag [32-63]
//                      || energies(t+1) after flag [64-191] ----------------
__global__ __launch_bounds__(512) void ge_kernel(
        const float* __restrict__ abih, const float* __restrict__ abhh,
        const float* __restrict__ qw,
        const float* __restrict__ dbih, const float* __restrict__ dbhh,
        const float* __restrict__ pjw, const float* __restrict__ pjb,
        const float* __restrict__ gtw, const float* __restrict__ gtb,
        const float* __restrict__ wc, const float* __restrict__ ldw,
        const float* __restrict__ vw, const int* __restrict__ mlen,
        float* __restrict__ ws, float* __restrict__ out, int t) {
    __shared__ float sm[5888];
    int tid = threadIdx.x, bid = blockIdx.x;
    unsigned* flg = (unsigned*)(ws + WS_FLG) + (t + 1);

    if (bid < 32) {                       // ---- dgates + proj (r12 verbatim) ----
        if (t < 0) return;
        int b = bid;
        float* DH = ws + WS_DH + (size_t)b * NU;
        float* DC = ws + WS_DC + (size_t)b * NU;
        for (int u = tid; u < NU; u += 512) {
            float zi = dbih[u]          + dbhh[u];
            float zf = dbih[NU + u]     + dbhh[NU + u];
            float zg = dbih[2 * NU + u] + dbhh[2 * NU + u];
            float zo = dbih[3 * NU + u] + dbhh[3 * NU + u];
            for (int s = 0; s < 20; s++) {
                const float* z = ws + WS_ZD + ((size_t)s * NB + b) * NG;
                zi += z[u]; zf += z[NU + u]; zg += z[2 * NU + u]; zo += z[3 * NU + u];
            }
            float c = fsigm(zf) * DC[u] + fsigm(zi) * ftanh(zg);
            float h = fsigm(zo) * ftanh(c);
            DC[u] = c; DH[u] = h; sm[u] = h;
        }
        for (int i = tid; i < NENC; i += 512) sm[NU + i] = ws[WS_ACTX + b * NENC + i];
        __syncthreads();
        int col = tid >> 2, q = tid & 3;
        if (col < 81) {
            const float* wr = (col < 80) ? (pjw + (size_t)col * 1536) : gtw;
            const float* d4 = sm + q * 384;
            const float* w4 = wr + q * 384;
            float s = 0.f;
#pragma unroll
            for (int k4 = 0; k4 < 96; k4++) {
                float4 hv = *(const float4*)(d4 + k4 * 4);
                float4 wv = *(const float4*)(w4 + k4 * 4);
                s = fmaf(hv.x, wv.x, s); s = fmaf(hv.y, wv.y, s);
                s = fmaf(hv.z, wv.z, s); s = fmaf(hv.w, wv.w, s);
            }
            s += __shfl_xor(s, 1); s += __shfl_xor(s, 2);
            if (q == 0) {
                s += (col < 80) ? pjb[col] : gtb[0];
                if (col < 80) out[((size_t)b * NMEL + col) * TOUT + t] = s;
                else          out[(size_t)NB * NMEL * TOUT + (size_t)b * TOUT + t] = s;
            }
        }
        return;
    }
    if (bid < 64) {                       // ---- agates + pq (t+1) + flag ----
        if (t + 1 >= TOUT) return;
        int b = bid - 32;
        float* AH = ws + WS_AH + (size_t)b * NU;
        float* AC = ws + WS_AC + (size_t)b * NU;
        for (int u = tid; u < NU; u += 512) {
            float zi = abih[u]          + abhh[u];
            float zf = abih[NU + u]     + abhh[NU + u];
            float zg = abih[2 * NU + u] + abhh[2 * NU + u];
            float zo = abih[3 * NU + u] + abhh[3 * NU + u];
            for (int s = 0; s < 14; s++) {
                const float* z = ws + WS_ZA + ((size_t)s * NB + b) * NG;
                zi += z[u]; zf += z[NU + u]; zg += z[2 * NU + u]; zo += z[3 * NU + u];
            }
            float c = fsigm(zf) * AC[u] + fsigm(zi) * ftanh(zg);
            float h = fsigm(zo) * ftanh(c);
            AC[u] = c; AH[u] = h; sm[u] = h;
        }
        __syncthreads();
        int a = tid >> 2, q = tid & 3;
        const float* qr = qw + (size_t)a * NU + q * 256;
        const float* h4 = sm + q * 256;
        float s = 0.f;
#pragma unroll
        for (int k4 = 0; k4 < 64; k4++) {
            float4 hv = *(const float4*)(h4 + k4 * 4);
            float4 wv = *(const float4*)(qr + k4 * 4);
            s = fmaf(hv.x, wv.x, s); s = fmaf(hv.y, wv.y, s);
            s = fmaf(hv.z, wv.z, s); s = fmaf(hv.w, wv.w, s);
        }
        s += __shfl_xor(s, 1); s += __shfl_xor(s, 2);
        if (q == 0) st_wt(&ws[WS_PQ + b * NATT + a], s);
        __syncthreads();                  // drains vmcnt -> pq at coherence point
        if (tid == 0)
            __hip_atomic_fetch_add(flg, 1u, __ATOMIC_RELAXED, __HIP_MEMORY_SCOPE_AGENT);
        return;
    }
    // ---- energies(t+1): 128 blocks, b = eb>>2, t-range (eb&3)*128 ----
    if (t + 1 >= TOUT) return;
    int eb = bid - 64;
    int b = eb >> 2, tc = eb & 3;
    int tt = tid & 127, sub = tid >> 7;
    int tp_ = tc * 128 + tt;
    float* awl  = sm;           // 512
    float* cuml = sm + 512;     // 512
    float* locl = sm + 1024;    // 128*33 = 4224
    float* pql  = sm + 5248;    // 128
    float* ep   = sm + 5376;    // 512
    for (int i = tid; i < TIN; i += 512) {
        awl[i]  = ws[WS_AW + b * TIN + i];
        cuml[i] = ws[WS_AWCUM + b * TIN + i];
    }
    if (tid == 0) {
        while (__hip_atomic_fetch_add(flg, 0u, __ATOMIC_RELAXED, __HIP_MEMORY_SCOPE_AGENT) < 32u)
            __builtin_amdgcn_s_sleep(8);
    }
    __syncthreads();
    if (tid < NATT)
        pql[tid] = __hip_atomic_load(&ws[WS_PQ + b * NATT + tid],
                                     __ATOMIC_RELAXED, __HIP_MEMORY_SCOPE_AGENT);
    __syncthreads();
    // conv: this thread's t, 8 filters
    {
        int f0 = sub * 8;
        float sA[8];
#pragma unroll
        for (int j = 0; j < 8; ++j) sA[j] = 0.f;
        for (int d = 0; d < 31; ++d) {
            int tp = tp_ + d - 15;
            int tc_ = min(max(tp, 0), 511);
            bool ok = (tp >= 0) && (tp < 512);
            float a_ = ok ? awl[tc_] : 0.f;
            float c_ = ok ? cuml[tc_] : 0.f;
#pragma unroll
            for (int j = 0; j < 8; ++j)
                sA[j] = fmaf(a_, wc[(f0 + j) * 62 + d], fmaf(c_, wc[(f0 + j) * 62 + 31 + d], sA[j]));
        }
#pragma unroll
        for (int j = 0; j < 8; ++j) locl[tt * 33 + f0 + j] = sA[j];
    }
    __syncthreads();
    {
        float acc = 0.0f;
        const float* pmb = ws + WS_PM + ((size_t)b * TIN + tp_) * NATT;
        for (int a = sub * 32; a < sub * 32 + 32; a++) {
            float s_ = pql[a] + pmb[a];
            const float* lw = ldw + a * 32;
#pragma unroll
            for (int f = 0; f < 32; f++) s_ += locl[tt * 33 + f] * lw[f];
            acc += tanhf(s_) * vw[a];
        }
        ep[tt * 4 + sub] = acc;
    }
    __syncthreads();
    if (sub == 0) {
        float ev = ep[tt * 4] + ep[tt * 4 + 1] + ep[tt * 4 + 2] + ep[tt * 4 + 3];
        if (tp_ >= mlen[b]) ev = -3.0e38f;
        ws[WS_E + b * TIN + tp_] = ev;
    }
}

extern "C" void kernel_launch(void* const* d_in, const int* in_sizes, int n_in,
                              void* d_out, int out_size, void* d_ws, size_t ws_size,
                              hipStream_t stream) {
    const float* memory = (const float*)d_in[0];
    const float* dec    = (const float*)d_in[1];
    const int*   mlen   = (const int*)d_in[2];
    const float* pw1    = (const float*)d_in[3];
    const float* pw2    = (const float*)d_in[4];
    const float* awih   = (const float*)d_in[5];
    const float* awhh   = (const float*)d_in[6];
    const float* abih   = (const float*)d_in[7];
    const float* abhh   = (const float*)d_in[8];
    const float* qw     = (const float*)d_in[9];
    const float* mw     = (const float*)d_in[10];
    const float* vw     = (const float*)d_in[11];
    const float* wc     = (const float*)d_in[12];
    const float* ldw    = (const float*)d_in[13];
    const float* dwih   = (const float*)d_in[14];
    const float* dwhh   = (const float*)d_in[15];
    const float* dbih   = (const float*)d_in[16];
    const float* dbhh   = (const float*)d_in[17];
    const float* pjw    = (const float*)d_in[18];
    const float* pjb    = (const float*)d_in[19];
    const float* gtw    = (const float*)d_in[20];
    const float* gtb    = (const float*)d_in[21];
    float* ws  = (float*)d_ws;
    float* out = (float*)d_out;
    float* out_align = out + OUT_ALIGN;
    unsigned short* wbf = (unsigned short*)(ws + WS_WBF);

    // zero state + flags (+ pre tail row)
    hipMemsetAsync(ws, 0, WS_STATE_ZERO_BYTES, stream);
    hipMemsetAsync(ws + WS_PRE + (size_t)512 * NB * NPRE, 0, (size_t)NB * NPRE * 4, stream);

    packbf_kernel<<<1024, 256, 0, stream>>>(dwih, wbf + BW_DIH, 4096 * 1536);
    packbf_kernel<<<1024, 256, 0, stream>>>(dwhh, wbf + BW_DHH, 4096 * 1024);
    packbf_kernel<<<1024, 256, 0, stream>>>(awih, wbf + BW_AIH, 4096 * 768);
    packbf_kernel<<<1024, 256, 0, stream>>>(awhh, wbf + BW_AHH, 4096 * 1024);

    prenet1_kernel<<<TOUT, 256, 0, stream>>>(dec, pw1, ws + WS_PRE);
    prenet2_kernel<<<TOUT, 256, 0, stream>>>(pw2, ws + WS_PRE);
    pm_kernel<<<dim3(TIN / 4, NB), 128, 0, stream>>>(memory, mw, ws + WS_PM);

    // prologue: z(0) on zeroed state (za(0) valid; zd garbage unused),
    // then GE(-1): agates(0)+pq(0)+flag -> energies(0)
    z_all_kernel<<<dim3(16, 34), 256, 0, stream>>>(
        wbf, ws, ws + WS_PRE, ws + WS_ZD, ws + WS_ZA);
    ge_kernel<<<192, 512, 0, stream>>>(abih, abhh, qw, dbih, dbhh, pjw, pjb,
                                       gtw, gtb, wc, ldw, vw, mlen, ws, out, -1);

    for (int t = 0; t < TOUT; ++t) {
        softmax_ctx_kernel<<<dim3(8, NB), 256, 0, stream>>>(
            memory, ws + WS_E, ws + WS_AW, ws + WS_AWCUM, ws + WS_ACTX, out_align, t);
        z_all_kernel<<<dim3(16, 34), 256, 0, stream>>>(
            wbf, ws, ws + WS_PRE + (size_t)(t + 1) * NB * NPRE, ws + WS_ZD, ws + WS_ZA);
        ge_kernel<<<192, 512, 0, stream>>>(abih, abhh, qw, dbih, dbhh, pjw, pjb,
                                           gtw, gtb, wc, ldw, vw, mlen, ws, out, t);
    }
}